// Round 9
// baseline (622.205 us; speedup 1.0000x reference)
//
#include <hip/hip_runtime.h>
#include <hip/hip_cooperative_groups.h>

namespace cg = cooperative_groups;

#define S 48
#define D 4
#define PADC 2
#define P 52
#define SITES (S * S * S)        // 110592
#define PADVOL (P * P * P)       // 140608
#define N_IN 2048
#define H1 1024
#define H2 128
#define OUTN 10
#define RP 64                    // rows per gemv1 block
#define NCH (SITES / RP)         // 1728
#define RG 16                    // row-groups in reduce stage A
#define CHPG (NCH / RG)          // 108 chunks per group
#define G2B 32                   // gemv2 blocks (rows of W2 per block = 32)
#define FBLK 864                 // cooperative front blocks (2 sites per 4-lane group)

__global__ __launch_bounds__(256) void zero_k(float4* __restrict__ p, int n4) {
    int i = blockIdx.x * 256 + threadIdx.x;
    if (i < n4) p[i] = make_float4(0.f, 0.f, 0.f, 0.f);
}

__global__ void scatter_k(const float* __restrict__ vin,
                          const int* __restrict__ idx,
                          float* __restrict__ nm) {
    int t = blockIdx.x * blockDim.x + threadIdx.x;
    if (t < N_IN) {
        int x = idx[t * 3 + 0] + PADC;
        int y = idx[t * 3 + 1] + PADC;
        int z = idx[t * 3 + 2] + PADC;
        atomicAdd(&nm[(x * P + y) * P + z], vin[t]);
    }
}

// Fallback per-step kernel (R7 proven): 4 lanes/site, 1728 blocks.
__global__ __launch_bounds__(256) void step_k(const float* __restrict__ src,
                                              const float* __restrict__ syn,
                                              float* __restrict__ dst) {
    int tid = threadIdx.x;
    int q = tid & 3;
    int sl = tid >> 2;
    int s = blockIdx.x * 64 + sl;
    int z = s % S;
    int t2 = s / S;
    int y = t2 % S;
    int x = t2 / S;
    const float4* sv = (const float4*)(syn + (size_t)s * 64);
    float acc = 0.0f;
#pragma unroll
    for (int a = 0; a < D; a++) {
        const float* row = src + ((x + a) * P + (y + q)) * P + z;
        float4 w = sv[a * 4 + q];
        acc += w.x * row[0] + w.y * row[1] + w.z * row[2] + w.w * row[3];
    }
    acc += __shfl_xor(acc, 1);
    acc += __shfl_xor(acc, 2);
    if (q == 0) {
        dst[((x + PADC) * P + (y + PADC)) * P + (z + PADC)] = fmaxf(acc, 0.0f) * 0.9f;
    }
}

// Cooperative front: zero -> scatter -> 5 steps with register-resident weights.
// 864 blocks x 256 threads; each 4-lane group owns 2 sites (32 weight VGPRs).
// __launch_bounds__(256,4): VGPR cap 128, guaranteed >=4 blocks/CU -> 1024
// co-resident blocks >= 864, so grid.sync() is valid.
__global__ __launch_bounds__(256, 4) void front_k(const float* __restrict__ vin,
                                                  const int* __restrict__ idx,
                                                  const float* __restrict__ syn,
                                                  float* __restrict__ nm0,
                                                  float* __restrict__ nm1) {
    cg::grid_group grid = cg::this_grid();
    int tid = threadIdx.x;
    int bid = blockIdx.x;
    int gt = bid * 256 + tid;

    // phase 0: zero both nm buffers (2*PADVOL floats = 70304 float4s)
    {
        float4* z4 = (float4*)nm0;
        if (gt < (2 * PADVOL) / 4) z4[gt] = make_float4(0.f, 0.f, 0.f, 0.f);
    }
    grid.sync();

    // phase 1: scatter-add inputs
    if (gt < N_IN) {
        int sx = idx[gt * 3 + 0] + PADC;
        int sy = idx[gt * 3 + 1] + PADC;
        int sz = idx[gt * 3 + 2] + PADC;
        atomicAdd(&nm0[(sx * P + sy) * P + sz], vin[gt]);
    }
    grid.sync();

    // phases 2..6: recurrence, 2 sites per 4-lane group, weights in registers
    int q = tid & 3;
    int sl = tid >> 2;                        // 0..63
    int s0 = bid * 128 + sl;
    int s1 = s0 + 64;
    int z0 = s0 % S, t0 = s0 / S, y0 = t0 % S, x0 = t0 / S;
    int z1 = s1 % S, t1 = s1 / S, y1 = t1 % S, x1 = t1 / S;
    const float4* sv0 = (const float4*)(syn + (size_t)s0 * 64);
    const float4* sv1 = (const float4*)(syn + (size_t)s1 * 64);
    float4 wa0 = sv0[0 * 4 + q], wa1 = sv0[1 * 4 + q];
    float4 wa2 = sv0[2 * 4 + q], wa3 = sv0[3 * 4 + q];
    float4 wb0 = sv1[0 * 4 + q], wb1 = sv1[1 * 4 + q];
    float4 wb2 = sv1[2 * 4 + q], wb3 = sv1[3 * 4 + q];
    const size_t ra = ((size_t)x0 * P + (y0 + q)) * P + z0;
    const size_t rb = ((size_t)x1 * P + (y1 + q)) * P + z1;
    const size_t oa = ((size_t)(x0 + PADC) * P + (y0 + PADC)) * P + (z0 + PADC);
    const size_t ob = ((size_t)(x1 + PADC) * P + (y1 + PADC)) * P + (z1 + PADC);
    const size_t PP = (size_t)P * P;

    const float* src = nm0;
    float* dst = nm1;
#pragma unroll 1
    for (int r = 0; r < 5; r++) {
        const float* pa = src + ra;
        const float* pb = src + rb;
        float acc0, acc1;
        acc0  = wa0.x * pa[0] + wa0.y * pa[1] + wa0.z * pa[2] + wa0.w * pa[3]; pa += PP;
        acc0 += wa1.x * pa[0] + wa1.y * pa[1] + wa1.z * pa[2] + wa1.w * pa[3]; pa += PP;
        acc0 += wa2.x * pa[0] + wa2.y * pa[1] + wa2.z * pa[2] + wa2.w * pa[3]; pa += PP;
        acc0 += wa3.x * pa[0] + wa3.y * pa[1] + wa3.z * pa[2] + wa3.w * pa[3];
        acc1  = wb0.x * pb[0] + wb0.y * pb[1] + wb0.z * pb[2] + wb0.w * pb[3]; pb += PP;
        acc1 += wb1.x * pb[0] + wb1.y * pb[1] + wb1.z * pb[2] + wb1.w * pb[3]; pb += PP;
        acc1 += wb2.x * pb[0] + wb2.y * pb[1] + wb2.z * pb[2] + wb2.w * pb[3]; pb += PP;
        acc1 += wb3.x * pb[0] + wb3.y * pb[1] + wb3.z * pb[2] + wb3.w * pb[3];
        acc0 += __shfl_xor(acc0, 1);
        acc0 += __shfl_xor(acc0, 2);
        acc1 += __shfl_xor(acc1, 1);
        acc1 += __shfl_xor(acc1, 2);
        if (q == 0) {
            dst[oa] = fmaxf(acc0, 0.0f) * 0.9f;
            dst[ob] = fmaxf(acc1, 0.0f) * 0.9f;
        }
        if (r < 4) {
            grid.sync();
            float* tmp = (float*)src;
            src = dst;
            dst = tmp;
        }
    }
    // result lives in nm1 (odd number of steps)
}

// Layer-1 GEMV: wave-uniform SGPR bitmask row skip, 4-way unrolled bit-loop.
__global__ __launch_bounds__(256) void gemv1_k(const float* __restrict__ nmfin,
                                               const float* __restrict__ W1,
                                               float* __restrict__ partial) {
    int t = threadIdx.x;
    int lane = t & 63;
    int i0 = blockIdx.x * RP;

    int i = i0 + lane;
    int z = i % S;
    int q = i / S;
    int y = q % S;
    int x = q / S;
    float v = nmfin[((x + PADC) * P + (y + PADC)) * P + (z + PADC)];
    unsigned long long mask = __ballot(v != 0.0f);

    const float4* W4 = (const float4*)W1;
    size_t base = (size_t)i0 * (H1 / 4) + t;
    float4 a0 = {0.f, 0.f, 0.f, 0.f};
    float4 a1 = {0.f, 0.f, 0.f, 0.f};
    float4 a2 = {0.f, 0.f, 0.f, 0.f};
    float4 a3 = {0.f, 0.f, 0.f, 0.f};
    int nnz = __popcll(mask);
    for (int k = 0; k + 4 <= nnz; k += 4) {
        int r0 = (int)__builtin_ctzll(mask); mask &= mask - 1;
        int r1 = (int)__builtin_ctzll(mask); mask &= mask - 1;
        int r2 = (int)__builtin_ctzll(mask); mask &= mask - 1;
        int r3 = (int)__builtin_ctzll(mask); mask &= mask - 1;
        float x0 = __int_as_float(__builtin_amdgcn_readlane(__float_as_int(v), r0));
        float x1 = __int_as_float(__builtin_amdgcn_readlane(__float_as_int(v), r1));
        float x2 = __int_as_float(__builtin_amdgcn_readlane(__float_as_int(v), r2));
        float x3 = __int_as_float(__builtin_amdgcn_readlane(__float_as_int(v), r3));
        float4 w0 = W4[base + (size_t)r0 * (H1 / 4)];
        float4 w1 = W4[base + (size_t)r1 * (H1 / 4)];
        float4 w2 = W4[base + (size_t)r2 * (H1 / 4)];
        float4 w3 = W4[base + (size_t)r3 * (H1 / 4)];
        a0.x += x0 * w0.x; a0.y += x0 * w0.y; a0.z += x0 * w0.z; a0.w += x0 * w0.w;
        a1.x += x1 * w1.x; a1.y += x1 * w1.y; a1.z += x1 * w1.z; a1.w += x1 * w1.w;
        a2.x += x2 * w2.x; a2.y += x2 * w2.y; a2.z += x2 * w2.z; a2.w += x2 * w2.w;
        a3.x += x3 * w3.x; a3.y += x3 * w3.y; a3.z += x3 * w3.z; a3.w += x3 * w3.w;
    }
    while (mask) {
        int r0 = (int)__builtin_ctzll(mask); mask &= mask - 1;
        float x0 = __int_as_float(__builtin_amdgcn_readlane(__float_as_int(v), r0));
        float4 w0 = W4[base + (size_t)r0 * (H1 / 4)];
        a0.x += x0 * w0.x; a0.y += x0 * w0.y; a0.z += x0 * w0.z; a0.w += x0 * w0.w;
    }
    float4 acc = {a0.x + a1.x + a2.x + a3.x,
                  a0.y + a1.y + a2.y + a3.y,
                  a0.z + a1.z + a2.z + a3.z,
                  a0.w + a1.w + a2.w + a3.w};
    ((float4*)(partial + (size_t)blockIdx.x * H1))[t] = acc;
}

__global__ __launch_bounds__(256) void reduceA_k(const float* __restrict__ partial,
                                                 float* __restrict__ redB) {
    int g = blockIdx.x >> 2;
    int c = (blockIdx.x & 3) * 256 + threadIdx.x;
    float s = 0.0f;
    int r0 = g * CHPG;
#pragma unroll 4
    for (int r = r0; r < r0 + CHPG; r++) s += partial[(size_t)r * H1 + c];
    redB[g * H1 + c] = s;
}

__global__ __launch_bounds__(128) void gemv2_k(const float* __restrict__ redB,
                                               const float* __restrict__ b1,
                                               const float* __restrict__ W2,
                                               float* __restrict__ partial2) {
    __shared__ float ys[H1 / G2B];            // 32
    int b = blockIdx.x;
    int t = threadIdx.x;
    int r0 = b * (H1 / G2B);
    if (t < H1 / G2B) {
        int j = r0 + t;
        float s = b1[j];
#pragma unroll
        for (int g = 0; g < RG; g++) s += redB[g * H1 + j];
        ys[t] = fmaxf(s, 0.0f);
    }
    __syncthreads();
    float acc = 0.0f;
#pragma unroll
    for (int i = 0; i < H1 / G2B; i++)
        acc += ys[i] * W2[(size_t)(r0 + i) * H2 + t];
    partial2[b * H2 + t] = acc;
}

__global__ __launch_bounds__(128) void final_k(const float* __restrict__ partial2,
                                               const float* __restrict__ b2,
                                               const float* __restrict__ W3,
                                               const float* __restrict__ b3,
                                               float* __restrict__ out) {
    __shared__ float y2[H2];
    int t = threadIdx.x;
    float s = b2[t];
#pragma unroll
    for (int k = 0; k < G2B; k++) s += partial2[k * H2 + t];
    y2[t] = fmaxf(s, 0.0f);
    __syncthreads();
    if (t < OUTN) {
        float o = b3[t];
#pragma unroll 8
        for (int i = 0; i < H2; i++) o += y2[i] * W3[i * OUTN + t];
        out[t] = o;
    }
}

extern "C" void kernel_launch(void* const* d_in, const int* in_sizes, int n_in,
                              void* d_out, int out_size, void* d_ws, size_t ws_size,
                              hipStream_t stream) {
    const float* vinput  = (const float*)d_in[1];
    const float* synapse = (const float*)d_in[2];
    const float* W1      = (const float*)d_in[3];
    const float* b1      = (const float*)d_in[4];
    const float* W2      = (const float*)d_in[5];
    const float* b2      = (const float*)d_in[6];
    const float* W3      = (const float*)d_in[7];
    const float* b3      = (const float*)d_in[8];
    const int* node_idx  = (const int*)d_in[9];

    float* ws = (float*)d_ws;
    float* nm0 = ws;                           // PADVOL
    float* nm1 = nm0 + PADVOL;                 // PADVOL
    float* partial1 = nm1 + PADVOL;            // NCH * 1024
    float* redB = partial1 + (size_t)NCH * H1; // 16 * 1024
    float* partial2 = redB + RG * H1;          // G2B * 128
    float* out = (float*)d_out;

    // cooperative front: zero + scatter + 5 steps, weights register-resident
    void* args[] = {(void*)&vinput, (void*)&node_idx, (void*)&synapse,
                    (void*)&nm0, (void*)&nm1};
    hipError_t ce = hipLaunchCooperativeKernel((void*)front_k, dim3(FBLK), dim3(256),
                                               args, 0, stream);
    if (ce != hipSuccess) {
        // fallback: R7 proven dispatch sequence (result also lands in nm1)
        const int n4 = 2 * PADVOL / 4;
        zero_k<<<(n4 + 255) / 256, 256, 0, stream>>>((float4*)nm0, n4);
        scatter_k<<<N_IN / 256, 256, 0, stream>>>(vinput, node_idx, nm0);
        const float* src = nm0;
        float* dst = nm1;
        for (int r = 0; r < 5; r++) {
            step_k<<<SITES / 64, 256, 0, stream>>>(src, synapse, dst);
            float* tmp = (float*)src;
            src = dst;
            dst = tmp;
        }
    }

    gemv1_k<<<NCH, 256, 0, stream>>>(nm1, W1, partial1);
    reduceA_k<<<RG * 4, 256, 0, stream>>>(partial1, redB);
    gemv2_k<<<G2B, 128, 0, stream>>>(redB, b1, W2, partial2);
    final_k<<<1, 128, 0, stream>>>(partial2, b2, W3, b3, out);
}

// Round 10
// 102.408 us; speedup vs baseline: 6.0757x; 6.0757x over previous
//
#include <hip/hip_runtime.h>

#define S 48
#define D 4
#define PADC 2
#define P 52
#define SITES (S * S * S)        // 110592
#define PADVOL (P * P * P)       // 140608
#define N_IN 2048
#define H1 1024
#define H2 128
#define OUTN 10
#define RP 64                    // rows per gemv1 block
#define NCH (SITES / RP)         // 1728
#define G2B 32                   // gemv2 blocks (32 y1-rows each)

__global__ __launch_bounds__(256) void zero_k(float4* __restrict__ p, int n4,
                                              int* __restrict__ cnt) {
    int i = blockIdx.x * 256 + threadIdx.x;
    if (i < n4) p[i] = make_float4(0.f, 0.f, 0.f, 0.f);
    if (i == 0) *cnt = 0;
}

__global__ void scatter_k(const float* __restrict__ vin,
                          const int* __restrict__ idx,
                          float* __restrict__ nm) {
    int t = blockIdx.x * blockDim.x + threadIdx.x;
    if (t < N_IN) {
        int x = idx[t * 3 + 0] + PADC;
        int y = idx[t * 3 + 1] + PADC;
        int z = idx[t * 3 + 2] + PADC;
        atomicAdd(&nm[(x * P + y) * P + z], vin[t]);
    }
}

// 4 lanes per site (proven R5/R7 config): lane-group of 4 splits the b-dim,
// combined with two shfl_xor. 1728 blocks -> 6.75 waves/SIMD.
__global__ __launch_bounds__(256) void step_k(const float* __restrict__ src,
                                              const float* __restrict__ syn,
                                              float* __restrict__ dst) {
    int tid = threadIdx.x;
    int q = tid & 3;                          // b-index
    int sl = tid >> 2;                        // 0..63
    int s = blockIdx.x * 64 + sl;
    int z = s % S;
    int t2 = s / S;
    int y = t2 % S;
    int x = t2 / S;
    const float4* sv = (const float4*)(syn + (size_t)s * 64);
    float acc = 0.0f;
#pragma unroll
    for (int a = 0; a < D; a++) {
        const float* row = src + ((x + a) * P + (y + q)) * P + z;
        float4 w = sv[a * 4 + q];
        acc += w.x * row[0] + w.y * row[1] + w.z * row[2] + w.w * row[3];
    }
    acc += __shfl_xor(acc, 1);
    acc += __shfl_xor(acc, 2);
    if (q == 0) {
        dst[((x + PADC) * P + (y + PADC)) * P + (z + PADC)] = fmaxf(acc, 0.0f) * 0.9f;
    }
}

// Layer-1 GEMV: wave-uniform SGPR bitmask row skip, 4-way unrolled bit-loop
// (4 float4 loads in flight), readlane broadcast (no LDS, no syncthreads).
__global__ __launch_bounds__(256) void gemv1_k(const float* __restrict__ nmfin,
                                               const float* __restrict__ W1,
                                               float* __restrict__ partial) {
    int t = threadIdx.x;
    int lane = t & 63;
    int i0 = blockIdx.x * RP;

    int i = i0 + lane;
    int z = i % S;
    int q = i / S;
    int y = q % S;
    int x = q / S;
    float v = nmfin[((x + PADC) * P + (y + PADC)) * P + (z + PADC)];
    unsigned long long mask = __ballot(v != 0.0f);

    const float4* W4 = (const float4*)W1;
    size_t base = (size_t)i0 * (H1 / 4) + t;
    float4 a0 = {0.f, 0.f, 0.f, 0.f};
    float4 a1 = {0.f, 0.f, 0.f, 0.f};
    float4 a2 = {0.f, 0.f, 0.f, 0.f};
    float4 a3 = {0.f, 0.f, 0.f, 0.f};
    int nnz = __popcll(mask);
    for (int k = 0; k + 4 <= nnz; k += 4) {
        int r0 = (int)__builtin_ctzll(mask); mask &= mask - 1;
        int r1 = (int)__builtin_ctzll(mask); mask &= mask - 1;
        int r2 = (int)__builtin_ctzll(mask); mask &= mask - 1;
        int r3 = (int)__builtin_ctzll(mask); mask &= mask - 1;
        float x0 = __int_as_float(__builtin_amdgcn_readlane(__float_as_int(v), r0));
        float x1 = __int_as_float(__builtin_amdgcn_readlane(__float_as_int(v), r1));
        float x2 = __int_as_float(__builtin_amdgcn_readlane(__float_as_int(v), r2));
        float x3 = __int_as_float(__builtin_amdgcn_readlane(__float_as_int(v), r3));
        float4 w0 = W4[base + (size_t)r0 * (H1 / 4)];
        float4 w1 = W4[base + (size_t)r1 * (H1 / 4)];
        float4 w2 = W4[base + (size_t)r2 * (H1 / 4)];
        float4 w3 = W4[base + (size_t)r3 * (H1 / 4)];
        a0.x += x0 * w0.x; a0.y += x0 * w0.y; a0.z += x0 * w0.z; a0.w += x0 * w0.w;
        a1.x += x1 * w1.x; a1.y += x1 * w1.y; a1.z += x1 * w1.z; a1.w += x1 * w1.w;
        a2.x += x2 * w2.x; a2.y += x2 * w2.y; a2.z += x2 * w2.z; a2.w += x2 * w2.w;
        a3.x += x3 * w3.x; a3.y += x3 * w3.y; a3.z += x3 * w3.z; a3.w += x3 * w3.w;
    }
    while (mask) {
        int r0 = (int)__builtin_ctzll(mask); mask &= mask - 1;
        float x0 = __int_as_float(__builtin_amdgcn_readlane(__float_as_int(v), r0));
        float4 w0 = W4[base + (size_t)r0 * (H1 / 4)];
        a0.x += x0 * w0.x; a0.y += x0 * w0.y; a0.z += x0 * w0.z; a0.w += x0 * w0.w;
    }
    float4 acc = {a0.x + a1.x + a2.x + a3.x,
                  a0.y + a1.y + a2.y + a3.y,
                  a0.z + a1.z + a2.z + a3.z,
                  a0.w + a1.w + a2.w + a3.w};
    ((float4*)(partial + (size_t)blockIdx.x * H1))[t] = acc;
}

// Fused tail: 32 blocks. Block b: (1) reduce its own 32-row slice of partial1
// over all 1728 chunks, (2) bias+relu -> ys, (3) 32x128 W2 partial GEMV ->
// partial2[b], (4) fence + arrival counter; the LAST block to arrive computes
// layer-2 finish + layer-3 (fixed summation order -> deterministic).
__global__ __launch_bounds__(128) void tail_k(const float* __restrict__ partial1,
                                              const float* __restrict__ b1,
                                              const float* __restrict__ W2,
                                              const float* __restrict__ b2,
                                              const float* __restrict__ W3,
                                              const float* __restrict__ b3,
                                              float* __restrict__ partial2,
                                              int* __restrict__ cnt,
                                              float* __restrict__ out) {
    __shared__ float ps[4][32];
    __shared__ float ys[32];
    __shared__ int amlast;
    int t = threadIdx.x;
    int b = blockIdx.x;
    int r0 = b * 32;
    int i = t & 31, g = t >> 5;
    float s = 0.0f;
#pragma unroll 8
    for (int r = g; r < NCH; r += 4)
        s += partial1[(size_t)r * H1 + r0 + i];
    ps[g][i] = s;
    __syncthreads();
    if (t < 32) {
        float sum = b1[r0 + t] + ps[0][t] + ps[1][t] + ps[2][t] + ps[3][t];
        ys[t] = fmaxf(sum, 0.0f);
    }
    __syncthreads();
    float acc = 0.0f;
#pragma unroll
    for (int k = 0; k < 32; k++)
        acc += ys[k] * W2[(size_t)(r0 + k) * H2 + t];
    partial2[b * H2 + t] = acc;

    // arrival: last block computes the final layers
    __threadfence();
    __syncthreads();
    if (t == 0) {
        int prev = atomicAdd(cnt, 1);
        amlast = (prev == G2B - 1) ? 1 : 0;
    }
    __syncthreads();
    if (amlast) {
        __threadfence();
        __shared__ float y2[H2];
        float s2 = b2[t];
#pragma unroll
        for (int k = 0; k < G2B; k++) s2 += partial2[k * H2 + t];
        y2[t] = fmaxf(s2, 0.0f);
        __syncthreads();
        if (t < OUTN) {
            float o = b3[t];
#pragma unroll 8
            for (int k = 0; k < H2; k++) o += y2[k] * W3[k * OUTN + t];
            out[t] = o;
        }
    }
}

extern "C" void kernel_launch(void* const* d_in, const int* in_sizes, int n_in,
                              void* d_out, int out_size, void* d_ws, size_t ws_size,
                              hipStream_t stream) {
    const float* vinput  = (const float*)d_in[1];
    const float* synapse = (const float*)d_in[2];
    const float* W1      = (const float*)d_in[3];
    const float* b1      = (const float*)d_in[4];
    const float* W2      = (const float*)d_in[5];
    const float* b2      = (const float*)d_in[6];
    const float* W3      = (const float*)d_in[7];
    const float* b3      = (const float*)d_in[8];
    const int* node_idx  = (const int*)d_in[9];

    float* ws = (float*)d_ws;
    float* nm0 = ws;                            // PADVOL
    float* nm1 = nm0 + PADVOL;                  // PADVOL
    float* partial1 = nm1 + PADVOL;             // NCH * 1024
    float* partial2 = partial1 + (size_t)NCH * H1; // G2B * 128
    int* cnt = (int*)(partial2 + G2B * H2);     // 1 int
    float* out = (float*)d_out;

    // zero both nm buffers + arrival counter
    const int n4 = 2 * PADVOL / 4;              // 70304 float4s
    zero_k<<<(n4 + 255) / 256, 256, 0, stream>>>((float4*)nm0, n4, cnt);

    scatter_k<<<N_IN / 256, 256, 0, stream>>>(vinput, node_idx, nm0);

    const float* src = nm0;
    float* dst = nm1;
    for (int r = 0; r < 5; r++) {
        step_k<<<SITES / 64, 256, 0, stream>>>(src, synapse, dst);
        float* tmp = (float*)src;
        src = dst;
        dst = tmp;
    }
    // final interior lives in nm1 (5 steps)

    gemv1_k<<<NCH, 256, 0, stream>>>(nm1, W1, partial1);
    tail_k<<<G2B, 128, 0, stream>>>(partial1, b1, W2, b2, W3, b3,
                                    partial2, cnt, out);
}

// Round 11
// 99.814 us; speedup vs baseline: 6.2337x; 1.0260x over previous
//
#include <hip/hip_runtime.h>

#define S 48
#define D 4
#define PADC 2
#define P 52
#define SITES (S * S * S)        // 110592
#define PADVOL (P * P * P)       // 140608
#define N_IN 2048
#define H1 1024
#define H2 128
#define OUTN 10
#define RP 64                    // rows per gemv1 block
#define NCH (SITES / RP)         // 1728
#define RG 16                    // row-groups in reduce stage A
#define CHPG (NCH / RG)          // 108 chunks per group
#define G2B 32                   // gemv2 blocks (32 y1-rows each)

__global__ __launch_bounds__(256) void zero_k(float4* __restrict__ p, int n4,
                                              int* __restrict__ cnt) {
    int i = blockIdx.x * 256 + threadIdx.x;
    if (i < n4) p[i] = make_float4(0.f, 0.f, 0.f, 0.f);
    if (i == 0) *cnt = 0;
}

__global__ void scatter_k(const float* __restrict__ vin,
                          const int* __restrict__ idx,
                          float* __restrict__ nm) {
    int t = blockIdx.x * blockDim.x + threadIdx.x;
    if (t < N_IN) {
        int x = idx[t * 3 + 0] + PADC;
        int y = idx[t * 3 + 1] + PADC;
        int z = idx[t * 3 + 2] + PADC;
        atomicAdd(&nm[(x * P + y) * P + z], vin[t]);
    }
}

// 4 lanes per site (proven R5/R7 config): lane-group of 4 splits the b-dim,
// combined with two shfl_xor. 1728 blocks -> 6.75 waves/SIMD.
__global__ __launch_bounds__(256) void step_k(const float* __restrict__ src,
                                              const float* __restrict__ syn,
                                              float* __restrict__ dst) {
    int tid = threadIdx.x;
    int q = tid & 3;                          // b-index
    int sl = tid >> 2;                        // 0..63
    int s = blockIdx.x * 64 + sl;
    int z = s % S;
    int t2 = s / S;
    int y = t2 % S;
    int x = t2 / S;
    const float4* sv = (const float4*)(syn + (size_t)s * 64);
    float acc = 0.0f;
#pragma unroll
    for (int a = 0; a < D; a++) {
        const float* row = src + ((x + a) * P + (y + q)) * P + z;
        float4 w = sv[a * 4 + q];
        acc += w.x * row[0] + w.y * row[1] + w.z * row[2] + w.w * row[3];
    }
    acc += __shfl_xor(acc, 1);
    acc += __shfl_xor(acc, 2);
    if (q == 0) {
        dst[((x + PADC) * P + (y + PADC)) * P + (z + PADC)] = fmaxf(acc, 0.0f) * 0.9f;
    }
}

// Layer-1 GEMV with FUSED final recurrence step: each lane computes its own
// site's step-5 value (64 MACs over the window of nm_src, relu*0.9) -- the
// 4 waves of the block compute the same 64 sites redundantly (cheap, L2-hot
// syn) so ballot/readlane semantics stay wave-local. Then the proven
// SGPR-bitmask 4-way-unrolled W1 stream.
__global__ __launch_bounds__(256) void gemv1f_k(const float* __restrict__ src,
                                                const float* __restrict__ syn,
                                                const float* __restrict__ W1,
                                                float* __restrict__ partial) {
    int t = threadIdx.x;
    int lane = t & 63;
    int i0 = blockIdx.x * RP;

    // --- fused step 5 for site i0+lane ---
    int s = i0 + lane;
    int z = s % S;
    int q = s / S;
    int y = q % S;
    int x = q / S;
    const float4* sv = (const float4*)(syn + (size_t)s * 64);
    float sum = 0.0f;
#pragma unroll
    for (int a = 0; a < D; a++) {
#pragma unroll
        for (int b = 0; b < D; b++) {
            const float* row = src + ((x + a) * P + (y + b)) * P + z;
            float4 w = sv[a * 4 + b];
            sum += w.x * row[0] + w.y * row[1] + w.z * row[2] + w.w * row[3];
        }
    }
    float v = fmaxf(sum, 0.0f) * 0.9f;
    unsigned long long mask = __ballot(v != 0.0f);

    const float4* W4 = (const float4*)W1;
    size_t base = (size_t)i0 * (H1 / 4) + t;
    float4 a0 = {0.f, 0.f, 0.f, 0.f};
    float4 a1 = {0.f, 0.f, 0.f, 0.f};
    float4 a2 = {0.f, 0.f, 0.f, 0.f};
    float4 a3 = {0.f, 0.f, 0.f, 0.f};
    int nnz = __popcll(mask);
    for (int k = 0; k + 4 <= nnz; k += 4) {
        int r0 = (int)__builtin_ctzll(mask); mask &= mask - 1;
        int r1 = (int)__builtin_ctzll(mask); mask &= mask - 1;
        int r2 = (int)__builtin_ctzll(mask); mask &= mask - 1;
        int r3 = (int)__builtin_ctzll(mask); mask &= mask - 1;
        float x0 = __int_as_float(__builtin_amdgcn_readlane(__float_as_int(v), r0));
        float x1 = __int_as_float(__builtin_amdgcn_readlane(__float_as_int(v), r1));
        float x2 = __int_as_float(__builtin_amdgcn_readlane(__float_as_int(v), r2));
        float x3 = __int_as_float(__builtin_amdgcn_readlane(__float_as_int(v), r3));
        float4 w0 = W4[base + (size_t)r0 * (H1 / 4)];
        float4 w1 = W4[base + (size_t)r1 * (H1 / 4)];
        float4 w2 = W4[base + (size_t)r2 * (H1 / 4)];
        float4 w3 = W4[base + (size_t)r3 * (H1 / 4)];
        a0.x += x0 * w0.x; a0.y += x0 * w0.y; a0.z += x0 * w0.z; a0.w += x0 * w0.w;
        a1.x += x1 * w1.x; a1.y += x1 * w1.y; a1.z += x1 * w1.z; a1.w += x1 * w1.w;
        a2.x += x2 * w2.x; a2.y += x2 * w2.y; a2.z += x2 * w2.z; a2.w += x2 * w2.w;
        a3.x += x3 * w3.x; a3.y += x3 * w3.y; a3.z += x3 * w3.z; a3.w += x3 * w3.w;
    }
    while (mask) {
        int r0 = (int)__builtin_ctzll(mask); mask &= mask - 1;
        float x0 = __int_as_float(__builtin_amdgcn_readlane(__float_as_int(v), r0));
        float4 w0 = W4[base + (size_t)r0 * (H1 / 4)];
        a0.x += x0 * w0.x; a0.y += x0 * w0.y; a0.z += x0 * w0.z; a0.w += x0 * w0.w;
    }
    float4 acc = {a0.x + a1.x + a2.x + a3.x,
                  a0.y + a1.y + a2.y + a3.y,
                  a0.z + a1.z + a2.z + a3.z,
                  a0.w + a1.w + a2.w + a3.w};
    ((float4*)(partial + (size_t)blockIdx.x * H1))[t] = acc;
}

// reduce stage A (R7 proven distribution): 64 blocks x 256 threads.
__global__ __launch_bounds__(256) void reduceA_k(const float* __restrict__ partial,
                                                 float* __restrict__ redB) {
    int g = blockIdx.x >> 2;
    int c = (blockIdx.x & 3) * 256 + threadIdx.x;
    float s = 0.0f;
    int r0 = g * CHPG;
#pragma unroll 4
    for (int r = r0; r < r0 + CHPG; r++) s += partial[(size_t)r * H1 + c];
    redB[g * H1 + c] = s;
}

// gemv2 + fused final (arrival-counter last-block, R10-proven mechanism):
// block b computes y1 rows [b*32,b*32+32) from redB, its W2 partial, then
// the last block to arrive computes layer-2 finish + layer-3.
__global__ __launch_bounds__(128) void gemv2f_k(const float* __restrict__ redB,
                                                const float* __restrict__ b1,
                                                const float* __restrict__ W2,
                                                const float* __restrict__ b2,
                                                const float* __restrict__ W3,
                                                const float* __restrict__ b3,
                                                float* __restrict__ partial2,
                                                int* __restrict__ cnt,
                                                float* __restrict__ out) {
    __shared__ float ys[H1 / G2B];            // 32
    __shared__ int amlast;
    int b = blockIdx.x;
    int t = threadIdx.x;
    int r0 = b * (H1 / G2B);
    if (t < H1 / G2B) {
        int j = r0 + t;
        float s = b1[j];
#pragma unroll
        for (int g = 0; g < RG; g++) s += redB[g * H1 + j];
        ys[t] = fmaxf(s, 0.0f);
    }
    __syncthreads();
    float acc = 0.0f;
#pragma unroll
    for (int i = 0; i < H1 / G2B; i++)
        acc += ys[i] * W2[(size_t)(r0 + i) * H2 + t];
    partial2[b * H2 + t] = acc;

    __threadfence();
    __syncthreads();
    if (t == 0) {
        int prev = atomicAdd(cnt, 1);
        amlast = (prev == G2B - 1) ? 1 : 0;
    }
    __syncthreads();
    if (amlast) {
        __threadfence();
        __shared__ float y2[H2];
        float s2 = b2[t];
#pragma unroll
        for (int k = 0; k < G2B; k++) s2 += partial2[k * H2 + t];
        y2[t] = fmaxf(s2, 0.0f);
        __syncthreads();
        if (t < OUTN) {
            float o = b3[t];
#pragma unroll 8
            for (int k = 0; k < H2; k++) o += y2[k] * W3[k * OUTN + t];
            out[t] = o;
        }
    }
}

extern "C" void kernel_launch(void* const* d_in, const int* in_sizes, int n_in,
                              void* d_out, int out_size, void* d_ws, size_t ws_size,
                              hipStream_t stream) {
    const float* vinput  = (const float*)d_in[1];
    const float* synapse = (const float*)d_in[2];
    const float* W1      = (const float*)d_in[3];
    const float* b1      = (const float*)d_in[4];
    const float* W2      = (const float*)d_in[5];
    const float* b2      = (const float*)d_in[6];
    const float* W3      = (const float*)d_in[7];
    const float* b3      = (const float*)d_in[8];
    const int* node_idx  = (const int*)d_in[9];

    float* ws = (float*)d_ws;
    float* nm0 = ws;                            // PADVOL
    float* nm1 = nm0 + PADVOL;                  // PADVOL
    float* partial1 = nm1 + PADVOL;             // NCH * 1024
    float* redB = partial1 + (size_t)NCH * H1;  // 16 * 1024
    float* partial2 = redB + RG * H1;           // G2B * 128
    int* cnt = (int*)(partial2 + G2B * H2);     // 1 int
    float* out = (float*)d_out;

    // zero both nm buffers + arrival counter
    const int n4 = 2 * PADVOL / 4;              // 70304 float4s
    zero_k<<<(n4 + 255) / 256, 256, 0, stream>>>((float4*)nm0, n4, cnt);

    scatter_k<<<N_IN / 256, 256, 0, stream>>>(vinput, node_idx, nm0);

    // steps 1..4 as dispatches; step 5 fused into gemv1f
    const float* src = nm0;
    float* dst = nm1;
    for (int r = 0; r < 4; r++) {
        step_k<<<SITES / 64, 256, 0, stream>>>(src, synapse, dst);
        float* tmp = (float*)src;
        src = dst;
        dst = tmp;
    }
    // after 4 steps the state is back in nm0

    gemv1f_k<<<NCH, 256, 0, stream>>>(src, synapse, W1, partial1);
    reduceA_k<<<RG * 4, 256, 0, stream>>>(partial1, redB);
    gemv2f_k<<<G2B, 128, 0, stream>>>(redB, b1, W2, b2, W3, b3,
                                      partial2, cnt, out);
}